// Round 7
// baseline (3141.832 us; speedup 1.0000x reference)
//
#include <hip/hip_runtime.h>
#include <math.h>

#define S_LEN 1024
#define BATCH 2048
#define HID   128
#define MTILE 16
#define NBLK  (BATCH / MTILE)   // 128 blocks
#define INV2048 (1.0f / 2048.0f)

// ws layout, offsets in _Float16 elements. K-extended arrays are [128][160]:
// k<128 = real weights, k=128..130 = (bias, x0-coef, x1-coef), k=131..159 = 0.
#define H_M1H 0
#define H_M1L 20480
#define H_MSH 40960
#define H_MSL 61440
#define H_ASH 81920
#define H_ASL 102400
#define H_WMH 122880     // [128][128] WtauM[:,128:256] hi
#define H_WML 139264
#define H_WBH 155648     // [128][128] WtauAdp[:,128:256] hi
#define H_WBL 172032
#define OFF_PART_F 94208 // float index into ws for per-block partials

typedef _Float16 half8 __attribute__((ext_vector_type(8)));
typedef _Float16 half4 __attribute__((ext_vector_type(4)));
typedef float floatx4 __attribute__((ext_vector_type(4)));

#define MFMA(a, b, c) __builtin_amdgcn_mfma_f32_16x16x32_f16((a), (b), (c), 0, 0, 0)

__device__ __forceinline__ void put_hl(_Float16* ws, int hiBase, int loBase,
                                       int idx, float v) {
  _Float16 hi = (_Float16)v;
  ws[hiBase + idx] = hi;
  ws[loBase + idx] = (_Float16)((v - (float)hi) * 2048.0f);
}

// ---- prep: fold dense->tau coupling + all per-h scalars into f16 hi/lo
// fragment-ready arrays.
__global__ __launch_bounds__(192) void prep(
    const float* __restrict__ W1x, const float* __restrict__ b1x,
    const float* __restrict__ WtauM, const float* __restrict__ btauM,
    const float* __restrict__ WtauAdp, const float* __restrict__ btauAdp,
    _Float16* __restrict__ ws) {
  const int h = blockIdx.x, k = threadIdx.x;
  if (k >= 160) return;
  if (k < 128) {
    float w1 = W1x[h * 130 + 2 + k];
    float s1 = 0.f, s2 = 0.f;
    for (int d = 0; d < 128; ++d) {
      float wd = W1x[d * 130 + 2 + k];
      s1 += WtauM[h * 256 + d] * wd;
      s2 += WtauAdp[h * 256 + d] * wd;
    }
    put_hl(ws, H_M1H, H_M1L, h * 160 + k, w1);
    put_hl(ws, H_MSH, H_MSL, h * 160 + k, s1);
    put_hl(ws, H_ASH, H_ASL, h * 160 + k, s2);
    put_hl(ws, H_WMH, H_WML, h * 128 + k, WtauM[h * 256 + 128 + k]);
    put_hl(ws, H_WBH, H_WBL, h * 128 + k, WtauAdp[h * 256 + 128 + k]);
  } else if (k < 131) {
    const int col = k - 128;   // 0: bias, 1: x0-coef, 2: x1-coef
    float m1v = (col == 0) ? b1x[h] : W1x[h * 130 + (col - 1)];
    float sm = 0.f, sa = 0.f;
    for (int d = 0; d < 128; ++d) {
      float cv = (col == 0) ? b1x[d] : W1x[d * 130 + (col - 1)];
      sm += WtauM[h * 256 + d] * cv;
      sa += WtauAdp[h * 256 + d] * cv;
    }
    if (col == 0) { sm += btauM[h]; sa += btauAdp[h]; }
    put_hl(ws, H_M1H, H_M1L, h * 160 + k, m1v);
    put_hl(ws, H_MSH, H_MSL, h * 160 + k, sm);
    put_hl(ws, H_ASH, H_ASL, h * 160 + k, sa);
  } else {
    put_hl(ws, H_M1H, H_M1L, h * 160 + k, 0.f);
    put_hl(ws, H_MSH, H_MSL, h * 160 + k, 0.f);
    put_hl(ws, H_ASH, H_ASL, h * 160 + k, 0.f);
  }
}

// State planes in MFMA B-fragment slab order: slab f (1 KB) holds, at
// half-index lane*8, B[n=lane&15][k=f*32+(lane>>4)*8 .. +8) -> every
// ds_read_b128 is lane-contiguous. bx slabs hold the per-step [1,x0,x1,0..]
// K-extension operand (hi/lo).
struct SLds {
  _Float16 spk[2][2048];
  _Float16 mH[2][2048], mL[2][2048];
  _Float16 bH[2][2048], bL[2][2048];
  _Float16 bxh[2][512], bxl[2][512];
  float red[8][16];
  float red2[16];
};

// 8 waves x 16-h slices; 2 waves/SIMD for MFMA<->VALU/LDS co-scheduling.
__global__ __launch_bounds__(512, 2) void snn_main(
    const float* __restrict__ x, const float* __restrict__ y,
    const float* __restrict__ h0m, const float* __restrict__ h0s,
    const float* __restrict__ h0b,
    const float* __restrict__ Wlin, const float* __restrict__ blin,
    const _Float16* __restrict__ W, float* __restrict__ wsout) {
  __shared__ SLds L;

  const int tid  = threadIdx.x;
  const int w    = tid >> 6;      // wave 0..7, owns h-slice [16w, 16w+16)
  const int lane = tid & 63;
  const int c    = lane & 15;
  const int q    = lane >> 4;
  const int bbase = blockIdx.x * MTILE;

  // ---- Register-resident A-frag weights (~184 regs, MFMA-only -> AGPR side)
  half8 m1h[5], m1l[5], msh[5], msl[5], ash[5], asl[5];
  half8 wmh[4], wml[4], wbh[4], wbl[4];
  {
    const int hA = w * 16 + c;
#pragma unroll
    for (int f = 0; f < 5; ++f) {
      const int o = hA * 160 + f * 32 + q * 8;
      m1h[f] = *(const half8*)&W[H_M1H + o];
      m1l[f] = *(const half8*)&W[H_M1L + o];
      msh[f] = *(const half8*)&W[H_MSH + o];
      msl[f] = *(const half8*)&W[H_MSL + o];
      ash[f] = *(const half8*)&W[H_ASH + o];
      asl[f] = *(const half8*)&W[H_ASL + o];
    }
#pragma unroll
    for (int f = 0; f < 4; ++f) {
      const int o = hA * 128 + f * 32 + q * 8;
      wmh[f] = *(const half8*)&W[H_WMH + o];
      wml[f] = *(const half8*)&W[H_WML + o];
      wbh[f] = *(const half8*)&W[H_WBH + o];
      wbl[f] = *(const half8*)&W[H_WBL + o];
    }
  }

  // ---- Per-lane recurrent state in C layout: (h = w*16 + q*4 + r, b = c)
  float memv[4], spk[4], bb[4];
#pragma unroll
  for (int r = 0; r < 4; ++r) {
    const int gi = (bbase + c) * HID + w * 16 + q * 4 + r;
    memv[r] = h0m[gi]; spk[r] = h0s[gi]; bb[r] = h0b[gi];
  }

  // ---- Zero bx slabs (2048 halves total; guard for 512 threads)
  if (tid < 256) {
    _Float16* bz = (_Float16*)L.bxh;
    *(half8*)&bz[tid * 8] = half8{0, 0, 0, 0, 0, 0, 0, 0};
  }

  // ---- Initialize plane buf 0 in slab order (waves 0..2 take one unit each)
  if (w < 3) {
    const float* src = (w == 0) ? h0s : (w == 1) ? h0m : h0b;
#pragma unroll
    for (int f = 0; f < 4; ++f) {
      const int gbase = (bbase + c) * HID + f * 32 + q * 8;
      half8 hi8, lo8;
#pragma unroll
      for (int j = 0; j < 8; ++j) {
        float v = src[gbase + j];
        _Float16 hi = (_Float16)v;
        hi8[j] = hi; lo8[j] = (_Float16)((v - (float)hi) * 2048.0f);
      }
      const int off = f * 512 + lane * 8;
      if (w == 0) { *(half8*)&L.spk[0][off] = hi8; }
      else if (w == 1) { *(half8*)&L.mH[0][off] = hi8; *(half8*)&L.mL[0][off] = lo8; }
      else { *(half8*)&L.bH[0][off] = hi8; *(half8*)&L.bL[0][off] = lo8; }
    }
  }
  __syncthreads();   // bx zeros + planes visible before bx[0] value writes

  if (tid < 16) {
    float2 x0 = *(const float2*)&x[(size_t)(bbase + tid) * 2];
    _Float16 x0h = (_Float16)x0.x, x1h = (_Float16)x0.y;
    half8 bh = {(_Float16)1.0f, x0h, x1h, 0, 0, 0, 0, 0};
    half8 bl = {0, (_Float16)((x0.x - (float)x0h) * 2048.0f),
                   (_Float16)((x0.y - (float)x1h) * 2048.0f), 0, 0, 0, 0, 0};
    *(half8*)&L.bxh[0][tid * 8] = bh;
    *(half8*)&L.bxl[0][tid * 8] = bl;
  }

  // Slab-order write offset for this lane's 4 consecutive C rows (b64)
  const int wo = (w >> 1) * 512 + (c + 16 * ((w & 1) * 2 + (q >> 1))) * 8
               + (q & 1) * 4;

  __syncthreads();

#pragma unroll 1
  for (int t = 0; t < S_LEN; ++t) {
    const int p = t & 1, pn = p ^ 1;
    const int rb = lane * 8;

    floatx4 dh = {0.f,0.f,0.f,0.f}, dl = {0.f,0.f,0.f,0.f};
    floatx4 mh = {0.f,0.f,0.f,0.f}, ml = {0.f,0.f,0.f,0.f};
    floatx4 ah = {0.f,0.f,0.f,0.f}, al = {0.f,0.f,0.f,0.f};

#pragma unroll
    for (int f = 0; f < 4; ++f) {
      const int off = f * 512 + rb;
      half8 bs  = *(const half8*)&L.spk[p][off];
      half8 xmh = *(const half8*)&L.mH[p][off];
      half8 xml = *(const half8*)&L.mL[p][off];
      half8 xbh = *(const half8*)&L.bH[p][off];
      half8 xbl = *(const half8*)&L.bL[p][off];
      dh = MFMA(m1h[f], bs, dh);
      dl = MFMA(m1l[f], bs, dl);
      mh = MFMA(msh[f], bs, mh);
      ml = MFMA(msl[f], bs, ml);
      mh = MFMA(wmh[f], xmh, mh);
      ml = MFMA(wmh[f], xml, ml);
      ml = MFMA(wml[f], xmh, ml);
      ah = MFMA(ash[f], bs, ah);
      al = MFMA(asl[f], bs, al);
      ah = MFMA(wbh[f], xbh, ah);
      al = MFMA(wbh[f], xbl, al);
      al = MFMA(wbl[f], xbh, al);
    }
    {  // K-extension chunk: bias + x coupling via [1,x0,x1] fragment
      half8 bxh8 = *(const half8*)&L.bxh[p][rb];
      half8 bxl8 = *(const half8*)&L.bxl[p][rb];
      dh = MFMA(m1h[4], bxh8, dh);
      dl = MFMA(m1l[4], bxh8, dl);
      dl = MFMA(m1h[4], bxl8, dl);
      mh = MFMA(msh[4], bxh8, mh);
      ml = MFMA(msl[4], bxh8, ml);
      ml = MFMA(msh[4], bxl8, ml);
      ah = MFMA(ash[4], bxh8, ah);
      al = MFMA(asl[4], bxh8, al);
      al = MFMA(ash[4], bxl8, al);
    }

    // ---- Elementwise update + packed b64 slab writes
    half4 ps, mh4, ml4, bh4, bl4;
#pragma unroll
    for (int r = 0; r < 4; ++r) {
      float den  = dh[r] + dl[r] * INV2048;
      float preM = mh[r] + ml[r] * INV2048;
      float preA = ah[r] + al[r] * INV2048;
      float tM = __builtin_amdgcn_rcpf(1.0f + __expf(-preM));
      float tA = __builtin_amdgcn_rcpf(1.0f + __expf(-preA));
      bb[r] = tA * bb[r] + (1.0f - tA) * spk[r];
      float Bth = 0.01f + 1.8f * bb[r];
      memv[r] = memv[r] * tM + (1.0f - tM) * den - Bth * spk[r];
      spk[r] = (memv[r] - Bth) > 0.0f ? 1.0f : 0.0f;
      ps[r] = (_Float16)spk[r];
      float v = memv[r]; _Float16 hi = (_Float16)v;
      mh4[r] = hi; ml4[r] = (_Float16)((v - (float)hi) * 2048.0f);
      v = bb[r]; hi = (_Float16)v;
      bh4[r] = hi; bl4[r] = (_Float16)((v - (float)hi) * 2048.0f);
    }
    *(half4*)&L.spk[pn][wo] = ps;
    *(half4*)&L.mH[pn][wo] = mh4; *(half4*)&L.mL[pn][wo] = ml4;
    *(half4*)&L.bH[pn][wo] = bh4; *(half4*)&L.bL[pn][wo] = bl4;

    if (tid < 16) {   // stage next step's K-extension fragment
      const size_t tn = (t + 1 < S_LEN) ? (size_t)(t + 1) : (size_t)t;
      float2 xn = *(const float2*)&x[(tn * BATCH + bbase + tid) * 2];
      _Float16 x0h = (_Float16)xn.x, x1h = (_Float16)xn.y;
      half8 bhx = {(_Float16)1.0f, x0h, x1h, 0, 0, 0, 0, 0};
      half8 blx = {0, (_Float16)((xn.x - (float)x0h) * 2048.0f),
                      (_Float16)((xn.y - (float)x1h) * 2048.0f), 0, 0, 0, 0, 0};
      *(half8*)&L.bxh[pn][tid * 8] = bhx;
      *(half8*)&L.bxl[pn][tid * 8] = blx;
    }
    __syncthreads();
  }

  // ---- Readout: out[b] = mem[b,:] @ Wlin + blin; per-block loss partial
  float part = 0.0f;
#pragma unroll
  for (int r = 0; r < 4; ++r)
    part += memv[r] * Wlin[w * 16 + q * 4 + r];
  part += __shfl_xor(part, 16);
  part += __shfl_xor(part, 32);   // sum over q: lane has wave partial for batch c
  if (lane < 16) L.red[w][c] = part;
  __syncthreads();
  if (tid < 16) {
    float s = 0.0f;
#pragma unroll
    for (int ww = 0; ww < 8; ++ww) s += L.red[ww][tid];
    float out = s + blin[0];
    float d = out - y[bbase + tid];
    L.red2[tid] = d * d;
  }
  __syncthreads();
  if (tid == 0) {
    float s = 0.0f;
#pragma unroll
    for (int m = 0; m < 16; ++m) s += L.red2[m];
    wsout[blockIdx.x] = s;
  }
}

__global__ __launch_bounds__(128) void final_reduce(const float* __restrict__ part,
                                                    float* __restrict__ out) {
  __shared__ float sh[128];
  int t = threadIdx.x;
  sh[t] = part[t];
  __syncthreads();
  for (int s = 64; s > 0; s >>= 1) {
    if (t < s) sh[t] += sh[t + s];
    __syncthreads();
  }
  if (t == 0) out[0] = sh[0] * (1.0f / (float)BATCH);
}

extern "C" void kernel_launch(void* const* d_in, const int* in_sizes, int n_in,
                              void* d_out, int out_size, void* d_ws, size_t ws_size,
                              hipStream_t stream) {
  const float* x       = (const float*)d_in[0];
  const float* y       = (const float*)d_in[1];
  const float* h0m     = (const float*)d_in[2];
  const float* h0s     = (const float*)d_in[3];
  const float* h0b     = (const float*)d_in[4];
  const float* W1x     = (const float*)d_in[5];
  const float* b1x     = (const float*)d_in[6];
  const float* WtauM   = (const float*)d_in[7];
  const float* btauM   = (const float*)d_in[8];
  const float* WtauAdp = (const float*)d_in[9];
  const float* btauAdp = (const float*)d_in[10];
  const float* Wlin    = (const float*)d_in[11];
  const float* blin    = (const float*)d_in[12];
  _Float16* wsf16 = (_Float16*)d_ws;
  float* wspart = (float*)d_ws + OFF_PART_F;

  prep<<<128, 192, 0, stream>>>(W1x, b1x, WtauM, btauM, WtauAdp, btauAdp, wsf16);
  snn_main<<<NBLK, 512, 0, stream>>>(x, y, h0m, h0s, h0b, Wlin, blin,
                                     wsf16, wspart);
  final_reduce<<<1, 128, 0, stream>>>(wspart, (float*)d_out);
}